// Round 1
// baseline (11051.562 us; speedup 1.0000x reference)
//
#include <hip/hip_runtime.h>
#include <hip/hip_bf16.h>

#define DFEAT 128
#define BETA 0.1f

// ---------------- in-degree count ----------------
__global__ void count_indeg(const int* __restrict__ dst, int* __restrict__ indeg, int E) {
    int e = blockIdx.x * blockDim.x + threadIdx.x;
    if (e < E) atomicAdd(&indeg[dst[e]], 1);
}

__global__ void make_norm(const int* __restrict__ indeg, float* __restrict__ norm, int N) {
    int n = blockIdx.x * blockDim.x + threadIdx.x;
    if (n < N) {
        float v = (float)(indeg[n] > 1 ? indeg[n] : 1);
        norm[n] = 1.0f / sqrtf(v);
    }
}

// ---------------- scatter hop ----------------
// val = (first ? h0[s] : agg_prev[s]*0.9 + h0[s]*0.1) * norm[s] * w[e]
// agg_new[dst] += val      (atomic, per float)
__global__ void scatter_hop(const float* __restrict__ hprev,  // agg_prev (or features if first)
                            const float* __restrict__ h0,     // features
                            const float* __restrict__ norm,
                            const int* __restrict__ src,
                            const int* __restrict__ dst,
                            const float* __restrict__ w,      // edge_factors for this graph
                            float* __restrict__ aggnew,
                            int E, int first_hop) {
    int tid = blockIdx.x * blockDim.x + threadIdx.x;
    int e = tid >> 5;            // 32 threads per edge
    if (e >= E) return;
    int c = (tid & 31) << 2;     // feature chunk offset (float4)

    int s = src[e];
    int d = dst[e];
    float scale = w[e] * norm[s];

    size_t soff = (size_t)s * DFEAT + c;
    float4 v = *(const float4*)(hprev + soff);
    if (!first_hop) {
        float4 v0 = *(const float4*)(h0 + soff);
        v.x = v.x * (1.0f - BETA) + v0.x * BETA;
        v.y = v.y * (1.0f - BETA) + v0.y * BETA;
        v.z = v.z * (1.0f - BETA) + v0.z * BETA;
        v.w = v.w * (1.0f - BETA) + v0.w * BETA;
    }
    v.x *= scale; v.y *= scale; v.z *= scale; v.w *= scale;

    float* out = aggnew + (size_t)d * DFEAT + c;
    unsafeAtomicAdd(out + 0, v.x);
    unsafeAtomicAdd(out + 1, v.y);
    unsafeAtomicAdd(out + 2, v.z);
    unsafeAtomicAdd(out + 3, v.w);
}

// ---------------- fused epilogue GEMM ----------------
// h = agg*0.9 + h0*0.1 ; out[:, g*128:(g+1)*128] = relu(h @ W[g] + b[g])
#define GROWS 128
__global__ __launch_bounds__(256) void gemm_out(const float* __restrict__ aggf,
                                                const float* __restrict__ h0,
                                                const float* __restrict__ W,   // W[g] base
                                                const float* __restrict__ b,   // b[g] base
                                                float* __restrict__ out,
                                                int N, int G, int g) {
    __shared__ float Wl[DFEAT * DFEAT];   // 64 KB
    __shared__ float Hl[8][DFEAT];        // 4 KB

    for (int i = threadIdx.x; i < DFEAT * DFEAT; i += 256) Wl[i] = W[i];

    int row0 = blockIdx.x * GROWS;
    int col  = threadIdx.x & 127;
    int rg   = threadIdx.x >> 7;          // 0..1
    float bias = b[col];

    int rend = row0 + GROWS;
    if (rend > N) rend = N;

    for (int rbase = row0; rbase < rend; rbase += 8) {
        __syncthreads();  // Wl ready (1st iter) / Hl consumed (later iters)
        for (int i = threadIdx.x; i < 8 * DFEAT; i += 256) {
            int r = rbase + (i >> 7);
            int k = i & 127;
            float hv = 0.0f;
            if (r < N) {
                size_t off = (size_t)r * DFEAT + k;
                hv = aggf[off] * (1.0f - BETA) + h0[off] * BETA;
            }
            Hl[i >> 7][k] = hv;
        }
        __syncthreads();

        float a0 = bias, a1 = bias, a2 = bias, a3 = bias;
        int rr = rg * 4;
        #pragma unroll 8
        for (int k = 0; k < DFEAT; k++) {
            float wv = Wl[k * DFEAT + col];
            a0 += Hl[rr + 0][k] * wv;
            a1 += Hl[rr + 1][k] * wv;
            a2 += Hl[rr + 2][k] * wv;
            a3 += Hl[rr + 3][k] * wv;
        }

        float acc[4] = {a0, a1, a2, a3};
        #pragma unroll
        for (int i = 0; i < 4; i++) {
            int r = rbase + rr + i;
            if (r < N) out[(size_t)r * (G * DFEAT) + g * DFEAT + col] = fmaxf(acc[i], 0.0f);
        }
    }
}

extern "C" void kernel_launch(void* const* d_in, const int* in_sizes, int n_in,
                              void* d_out, int out_size, void* d_ws, size_t ws_size,
                              hipStream_t stream) {
    const float* features = (const float*)d_in[0];
    const int*   src      = (const int*)d_in[1];
    const int*   dst      = (const int*)d_in[2];
    const float* efac     = (const float*)d_in[3];
    const float* W        = (const float*)d_in[4];
    const float* b        = (const float*)d_in[5];
    float* out = (float*)d_out;

    int N = in_sizes[0] / DFEAT;
    int E = in_sizes[1];
    int G = in_sizes[3] / E;

    // ws layout
    char* ws = (char*)d_ws;
    float* norm  = (float*)(ws);                       // N floats
    int*   indeg = (int*)(ws + ((size_t)N * 4 + 255 & ~255ull));
    size_t aggOff = (((size_t)N * 4 + 255) & ~255ull) * 2;
    size_t aggBytes = (size_t)N * DFEAT * sizeof(float);
    float* aggA = (float*)(ws + ((aggOff + 255) & ~255ull));
    float* aggB = (float*)((char*)aggA + ((aggBytes + 255) & ~255ull));

    // degree + norm
    hipMemsetAsync(indeg, 0, (size_t)N * 4, stream);
    count_indeg<<<(E + 255) / 256, 256, 0, stream>>>(dst, indeg, E);
    make_norm<<<(N + 255) / 256, 256, 0, stream>>>(indeg, norm, N);

    int scatterBlocks = (int)(((size_t)E * 32 + 255) / 256);
    int gemmBlocks = (N + GROWS - 1) / GROWS;

    for (int g = 0; g < G; g++) {
        const float* w = efac + (size_t)g * E;
        float* bufs[2] = {aggA, aggB};
        const float* hprev = features;
        float* cur = nullptr;
        for (int hop = 0; hop < 4; hop++) {
            cur = bufs[hop & 1];
            hipMemsetAsync(cur, 0, aggBytes, stream);
            scatter_hop<<<scatterBlocks, 256, 0, stream>>>(
                hprev, features, norm, src, dst, w, cur, E, hop == 0 ? 1 : 0);
            hprev = cur;
        }
        gemm_out<<<gemmBlocks, 256, 0, stream>>>(
            cur, features, W + (size_t)g * DFEAT * DFEAT, b + (size_t)g * DFEAT,
            out, N, G, g);
    }
}

// Round 2
// 769.117 us; speedup vs baseline: 14.3692x; 14.3692x over previous
//
#include <hip/hip_runtime.h>
#include <hip/hip_bf16.h>

#define DFEAT 128
#define BETA 0.1f

// ---------------- in-degree count ----------------
__global__ void count_indeg(const int* __restrict__ dst, int* __restrict__ indeg, int E) {
    int e = blockIdx.x * blockDim.x + threadIdx.x;
    if (e < E) atomicAdd(&indeg[dst[e]], 1);
}

__global__ void make_norm(const int* __restrict__ indeg, float* __restrict__ norm, int N) {
    int n = blockIdx.x * blockDim.x + threadIdx.x;
    if (n < N) {
        float v = (float)(indeg[n] > 1 ? indeg[n] : 1);
        norm[n] = 1.0f / sqrtf(v);
    }
}

// ---------------- prefix scan (3-kernel) ----------------
__global__ void block_sums(const int* __restrict__ indeg, int* __restrict__ bsum, int N) {
    __shared__ int sh[256];
    int i = blockIdx.x * 256 + threadIdx.x;
    sh[threadIdx.x] = (i < N) ? indeg[i] : 0;
    __syncthreads();
    for (int s = 128; s > 0; s >>= 1) {
        if (threadIdx.x < s) sh[threadIdx.x] += sh[threadIdx.x + s];
        __syncthreads();
    }
    if (threadIdx.x == 0) bsum[blockIdx.x] = sh[0];
}

__global__ void scan_bsum(int* __restrict__ bsum, int nb) {
    __shared__ int sh[256];
    __shared__ int carry;
    if (threadIdx.x == 0) carry = 0;
    __syncthreads();
    for (int base = 0; base < nb; base += 256) {
        int i = base + threadIdx.x;
        int v = (i < nb) ? bsum[i] : 0;
        sh[threadIdx.x] = v;
        __syncthreads();
        for (int s = 1; s < 256; s <<= 1) {
            int t = (threadIdx.x >= s) ? sh[threadIdx.x - s] : 0;
            __syncthreads();
            sh[threadIdx.x] += t;
            __syncthreads();
        }
        int incl = sh[threadIdx.x];
        if (i < nb) bsum[i] = incl - v + carry;
        int total = sh[255];
        __syncthreads();
        if (threadIdx.x == 0) carry += total;
        __syncthreads();
    }
}

__global__ void scan_final(const int* __restrict__ indeg, const int* __restrict__ bsum,
                           int* __restrict__ rowptr, int* __restrict__ cursor, int N) {
    __shared__ int sh[256];
    int i = blockIdx.x * 256 + threadIdx.x;
    int v = (i < N) ? indeg[i] : 0;
    sh[threadIdx.x] = v;
    __syncthreads();
    for (int s = 1; s < 256; s <<= 1) {
        int t = (threadIdx.x >= s) ? sh[threadIdx.x - s] : 0;
        __syncthreads();
        sh[threadIdx.x] += t;
        __syncthreads();
    }
    int excl = sh[threadIdx.x] - v + bsum[blockIdx.x];
    if (i < N) { rowptr[i] = excl; cursor[i] = excl; }
    if (i == N - 1) rowptr[N] = excl + v;
}

// ---------------- CSR fill (counting sort by dst) ----------------
__global__ void fill_csr(const int* __restrict__ src, const int* __restrict__ dst,
                         const float* __restrict__ efac, int* __restrict__ cursor,
                         int* __restrict__ csrc, float* __restrict__ wsort,
                         int E, int G) {
    int e = blockIdx.x * blockDim.x + threadIdx.x;
    if (e >= E) return;
    int p = atomicAdd(&cursor[dst[e]], 1);
    csrc[p] = src[e];
    for (int g = 0; g < G; g++) wsort[(size_t)g * E + p] = efac[(size_t)g * E + e];
}

// ---------------- hn0 = features * norm ----------------
__global__ void prep_hn(const float* __restrict__ h0, const float* __restrict__ norm,
                        float* __restrict__ hn, int N) {
    int i = blockIdx.x * blockDim.x + threadIdx.x;
    if (i >= N * (DFEAT / 4)) return;
    int n = i >> 5;
    float nm = norm[n];
    float4 v = ((const float4*)h0)[i];
    v.x *= nm; v.y *= nm; v.z *= nm; v.w *= nm;
    ((float4*)hn)[i] = v;
}

// ---------------- gather hop ----------------
// acc = sum_{e: dst=n} w[e] * hn[src[e]]
// out[n] = (acc*0.9 + h0[n]*0.1) * (last ? 1 : norm[n])
__global__ __launch_bounds__(256) void gather_hop(
        const float* __restrict__ hn, const float* __restrict__ h0,
        const float* __restrict__ norm,
        const int* __restrict__ rowptr, const int* __restrict__ csrc,
        const float* __restrict__ wsort, float* __restrict__ outb,
        int N, int last) {
    int tid = blockIdx.x * blockDim.x + threadIdx.x;
    int n = tid >> 5;
    if (n >= N) return;
    int c = tid & 31;

    int beg = rowptr[n], end = rowptr[n + 1];
    float4 a0 = {0, 0, 0, 0}, a1 = {0, 0, 0, 0};
    int i = beg;
    for (; i + 1 < end; i += 2) {
        int s0 = csrc[i], s1 = csrc[i + 1];
        float w0 = wsort[i], w1 = wsort[i + 1];
        float4 v0 = ((const float4*)(hn + (size_t)s0 * DFEAT))[c];
        float4 v1 = ((const float4*)(hn + (size_t)s1 * DFEAT))[c];
        a0.x += v0.x * w0; a0.y += v0.y * w0; a0.z += v0.z * w0; a0.w += v0.w * w0;
        a1.x += v1.x * w1; a1.y += v1.y * w1; a1.z += v1.z * w1; a1.w += v1.w * w1;
    }
    if (i < end) {
        int s = csrc[i]; float wv = wsort[i];
        float4 v = ((const float4*)(hn + (size_t)s * DFEAT))[c];
        a0.x += v.x * wv; a0.y += v.y * wv; a0.z += v.z * wv; a0.w += v.w * wv;
    }
    float4 acc = {a0.x + a1.x, a0.y + a1.y, a0.z + a1.z, a0.w + a1.w};

    float4 f0 = ((const float4*)(h0 + (size_t)n * DFEAT))[c];
    float4 r;
    r.x = acc.x * (1.0f - BETA) + f0.x * BETA;
    r.y = acc.y * (1.0f - BETA) + f0.y * BETA;
    r.z = acc.z * (1.0f - BETA) + f0.z * BETA;
    r.w = acc.w * (1.0f - BETA) + f0.w * BETA;
    if (!last) {
        float nm = norm[n];
        r.x *= nm; r.y *= nm; r.z *= nm; r.w *= nm;
    }
    ((float4*)(outb + (size_t)n * DFEAT))[c] = r;
}

// ---------------- fused epilogue GEMM ----------------
// out[:, g*128:(g+1)*128] = relu(h @ W[g] + b[g])   (h already beta-mixed)
#define GROWS 128
__global__ __launch_bounds__(256) void gemm_out(const float* __restrict__ h,
                                                const float* __restrict__ W,
                                                const float* __restrict__ b,
                                                float* __restrict__ out,
                                                int N, int G, int g) {
    __shared__ float Wl[DFEAT * DFEAT];   // 64 KB
    __shared__ float Hl[8][DFEAT];        // 4 KB

    for (int i = threadIdx.x; i < DFEAT * DFEAT; i += 256) Wl[i] = W[i];

    int row0 = blockIdx.x * GROWS;
    int col  = threadIdx.x & 127;
    int rg   = threadIdx.x >> 7;
    float bias = b[col];

    int rend = row0 + GROWS;
    if (rend > N) rend = N;

    for (int rbase = row0; rbase < rend; rbase += 8) {
        __syncthreads();
        for (int i = threadIdx.x; i < 8 * DFEAT; i += 256) {
            int r = rbase + (i >> 7);
            int k = i & 127;
            Hl[i >> 7][k] = (r < N) ? h[(size_t)r * DFEAT + k] : 0.0f;
        }
        __syncthreads();

        float a0 = bias, a1 = bias, a2 = bias, a3 = bias;
        int rr = rg * 4;
        #pragma unroll 8
        for (int k = 0; k < DFEAT; k++) {
            float wv = Wl[k * DFEAT + col];
            a0 += Hl[rr + 0][k] * wv;
            a1 += Hl[rr + 1][k] * wv;
            a2 += Hl[rr + 2][k] * wv;
            a3 += Hl[rr + 3][k] * wv;
        }

        float acc[4] = {a0, a1, a2, a3};
        #pragma unroll
        for (int i = 0; i < 4; i++) {
            int r = rbase + rr + i;
            if (r < N) out[(size_t)r * (G * DFEAT) + g * DFEAT + col] = fmaxf(acc[i], 0.0f);
        }
    }
}

static inline size_t align256(size_t x) { return (x + 255) & ~(size_t)255; }

extern "C" void kernel_launch(void* const* d_in, const int* in_sizes, int n_in,
                              void* d_out, int out_size, void* d_ws, size_t ws_size,
                              hipStream_t stream) {
    const float* features = (const float*)d_in[0];
    const int*   src      = (const int*)d_in[1];
    const int*   dst      = (const int*)d_in[2];
    const float* efac     = (const float*)d_in[3];
    const float* W        = (const float*)d_in[4];
    const float* b        = (const float*)d_in[5];
    float* out = (float*)d_out;

    int N = in_sizes[0] / DFEAT;
    int E = in_sizes[1];
    int G = in_sizes[3] / E;
    int nb = (N + 255) / 256;

    size_t featBytes = (size_t)N * DFEAT * sizeof(float);

    char* p = (char*)d_ws;
    float* X      = (float*)p; p += align256(featBytes);
    float* Y      = (float*)p; p += align256(featBytes);
    int*   indeg  = (int*)p;   p += align256((size_t)N * 4);
    float* norm   = (float*)p; p += align256((size_t)N * 4);
    int*   rowptr = (int*)p;   p += align256((size_t)(N + 1) * 4);
    int*   cursor = (int*)p;   p += align256((size_t)N * 4);
    int*   bsum   = (int*)p;   p += align256((size_t)nb * 4);
    int*   csrc   = (int*)p;   p += align256((size_t)E * 4);
    float* wsort  = (float*)p; p += align256((size_t)G * E * 4);

    // ---- build norm + CSR (shared across graphs) ----
    hipMemsetAsync(indeg, 0, (size_t)N * 4, stream);
    count_indeg<<<(E + 255) / 256, 256, 0, stream>>>(dst, indeg, E);
    make_norm<<<(N + 255) / 256, 256, 0, stream>>>(indeg, norm, N);
    block_sums<<<nb, 256, 0, stream>>>(indeg, bsum, N);
    scan_bsum<<<1, 256, 0, stream>>>(bsum, nb);
    scan_final<<<nb, 256, 0, stream>>>(indeg, bsum, rowptr, cursor, N);
    fill_csr<<<(E + 255) / 256, 256, 0, stream>>>(src, dst, efac, cursor, csrc, wsort, E, G);

    int prepBlocks   = (N * (DFEAT / 4) + 255) / 256;
    int gatherBlocks = ((N * 32) + 255) / 256;
    int gemmBlocks   = (N + GROWS - 1) / GROWS;

    for (int g = 0; g < G; g++) {
        const float* wg = wsort + (size_t)g * E;
        // Y = features * norm  (= h1 * norm)
        prep_hn<<<prepBlocks, 256, 0, stream>>>(features, norm, Y, N);
        // 4 hops, ping-pong Y -> X -> Y -> X -> Y
        float* bufs[2] = {X, Y};
        const float* in = Y;
        float* cur = nullptr;
        for (int hop = 0; hop < 4; hop++) {
            cur = bufs[hop & 1];
            gather_hop<<<gatherBlocks, 256, 0, stream>>>(
                in, features, norm, rowptr, csrc, wg, cur, N, hop == 3 ? 1 : 0);
            in = cur;
        }
        gemm_out<<<gemmBlocks, 256, 0, stream>>>(
            cur, W + (size_t)g * DFEAT * DFEAT, b + (size_t)g * DFEAT, out, N, G, g);
    }
}

// Round 3
// 663.706 us; speedup vs baseline: 16.6513x; 1.1588x over previous
//
#include <hip/hip_runtime.h>
#include <hip/hip_bf16.h>

#define DFEAT 128
#define BETA 0.1f

// ---------------- in-degree count ----------------
__global__ void count_indeg(const int* __restrict__ dst, int* __restrict__ indeg, int E) {
    int e = blockIdx.x * blockDim.x + threadIdx.x;
    if (e < E) atomicAdd(&indeg[dst[e]], 1);
}

__global__ void make_norm(const int* __restrict__ indeg, float* __restrict__ norm, int N) {
    int n = blockIdx.x * blockDim.x + threadIdx.x;
    if (n < N) {
        float v = (float)(indeg[n] > 1 ? indeg[n] : 1);
        norm[n] = 1.0f / sqrtf(v);
    }
}

// ---------------- prefix scan (3-kernel) ----------------
__global__ void block_sums(const int* __restrict__ indeg, int* __restrict__ bsum, int N) {
    __shared__ int sh[256];
    int i = blockIdx.x * 256 + threadIdx.x;
    sh[threadIdx.x] = (i < N) ? indeg[i] : 0;
    __syncthreads();
    for (int s = 128; s > 0; s >>= 1) {
        if (threadIdx.x < s) sh[threadIdx.x] += sh[threadIdx.x + s];
        __syncthreads();
    }
    if (threadIdx.x == 0) bsum[blockIdx.x] = sh[0];
}

__global__ void scan_bsum(int* __restrict__ bsum, int nb) {
    __shared__ int sh[256];
    __shared__ int carry;
    if (threadIdx.x == 0) carry = 0;
    __syncthreads();
    for (int base = 0; base < nb; base += 256) {
        int i = base + threadIdx.x;
        int v = (i < nb) ? bsum[i] : 0;
        sh[threadIdx.x] = v;
        __syncthreads();
        for (int s = 1; s < 256; s <<= 1) {
            int t = (threadIdx.x >= s) ? sh[threadIdx.x - s] : 0;
            __syncthreads();
            sh[threadIdx.x] += t;
            __syncthreads();
        }
        int incl = sh[threadIdx.x];
        if (i < nb) bsum[i] = incl - v + carry;
        int total = sh[255];
        __syncthreads();
        if (threadIdx.x == 0) carry += total;
        __syncthreads();
    }
}

__global__ void scan_final(const int* __restrict__ indeg, const int* __restrict__ bsum,
                           int* __restrict__ rowptr, int* __restrict__ cursor, int N) {
    __shared__ int sh[256];
    int i = blockIdx.x * 256 + threadIdx.x;
    int v = (i < N) ? indeg[i] : 0;
    sh[threadIdx.x] = v;
    __syncthreads();
    for (int s = 1; s < 256; s <<= 1) {
        int t = (threadIdx.x >= s) ? sh[threadIdx.x - s] : 0;
        __syncthreads();
        sh[threadIdx.x] += t;
        __syncthreads();
    }
    int excl = sh[threadIdx.x] - v + bsum[blockIdx.x];
    if (i < N) { rowptr[i] = excl; cursor[i] = excl; }
    if (i == N - 1) rowptr[N] = excl + v;
}

// ---------------- CSR fill: counting sort by dst, packed (src, w) per graph ----
__global__ void fill_csr(const int* __restrict__ src, const int* __restrict__ dst,
                         const float* __restrict__ efac, int* __restrict__ cursor,
                         int2* __restrict__ epack, int E, int G) {
    int e = blockIdx.x * blockDim.x + threadIdx.x;
    if (e >= E) return;
    int p = atomicAdd(&cursor[dst[e]], 1);
    int s = src[e];
    for (int g = 0; g < G; g++) {
        epack[(size_t)g * E + p] = make_int2(s, __float_as_int(efac[(size_t)g * E + e]));
    }
}

// ---------------- hn0 = features * norm ----------------
__global__ void prep_hn(const float* __restrict__ h0, const float* __restrict__ norm,
                        float* __restrict__ hn, int N) {
    int i = blockIdx.x * blockDim.x + threadIdx.x;
    if (i >= N * (DFEAT / 4)) return;
    int n = i >> 5;
    float nm = norm[n];
    float4 v = ((const float4*)h0)[i];
    v.x *= nm; v.y *= nm; v.z *= nm; v.w *= nm;
    ((float4*)hn)[i] = v;
}

// ---------------- gather hop (4-edge unroll, packed meta) ----------------
__global__ __launch_bounds__(256) void gather_hop(
        const float* __restrict__ hn, const float* __restrict__ h0,
        const float* __restrict__ norm,
        const int* __restrict__ rowptr, const int2* __restrict__ ep,
        float* __restrict__ outb, int N, int last) {
    int tid = blockIdx.x * blockDim.x + threadIdx.x;
    int n = tid >> 5;
    if (n >= N) return;
    int c = tid & 31;

    int beg = rowptr[n], end = rowptr[n + 1];
    float4 a0 = {0, 0, 0, 0}, a1 = {0, 0, 0, 0}, a2 = {0, 0, 0, 0}, a3 = {0, 0, 0, 0};
    int i = beg;
    for (; i + 3 < end; i += 4) {
        int2 m0 = ep[i], m1 = ep[i + 1], m2 = ep[i + 2], m3 = ep[i + 3];
        float4 v0 = ((const float4*)(hn + (size_t)m0.x * DFEAT))[c];
        float4 v1 = ((const float4*)(hn + (size_t)m1.x * DFEAT))[c];
        float4 v2 = ((const float4*)(hn + (size_t)m2.x * DFEAT))[c];
        float4 v3 = ((const float4*)(hn + (size_t)m3.x * DFEAT))[c];
        float w0 = __int_as_float(m0.y), w1 = __int_as_float(m1.y);
        float w2 = __int_as_float(m2.y), w3 = __int_as_float(m3.y);
        a0.x += v0.x * w0; a0.y += v0.y * w0; a0.z += v0.z * w0; a0.w += v0.w * w0;
        a1.x += v1.x * w1; a1.y += v1.y * w1; a1.z += v1.z * w1; a1.w += v1.w * w1;
        a2.x += v2.x * w2; a2.y += v2.y * w2; a2.z += v2.z * w2; a2.w += v2.w * w2;
        a3.x += v3.x * w3; a3.y += v3.y * w3; a3.z += v3.z * w3; a3.w += v3.w * w3;
    }
    for (; i < end; ++i) {
        int2 m = ep[i];
        float wv = __int_as_float(m.y);
        float4 v = ((const float4*)(hn + (size_t)m.x * DFEAT))[c];
        a0.x += v.x * wv; a0.y += v.y * wv; a0.z += v.z * wv; a0.w += v.w * wv;
    }
    float4 acc;
    acc.x = (a0.x + a1.x) + (a2.x + a3.x);
    acc.y = (a0.y + a1.y) + (a2.y + a3.y);
    acc.z = (a0.z + a1.z) + (a2.z + a3.z);
    acc.w = (a0.w + a1.w) + (a2.w + a3.w);

    float4 f0 = ((const float4*)(h0 + (size_t)n * DFEAT))[c];
    float4 r;
    r.x = acc.x * (1.0f - BETA) + f0.x * BETA;
    r.y = acc.y * (1.0f - BETA) + f0.y * BETA;
    r.z = acc.z * (1.0f - BETA) + f0.z * BETA;
    r.w = acc.w * (1.0f - BETA) + f0.w * BETA;
    if (!last) {
        float nm = norm[n];
        r.x *= nm; r.y *= nm; r.z *= nm; r.w *= nm;
    }
    ((float4*)(outb + (size_t)n * DFEAT))[c] = r;
}

// ---------------- epilogue GEMM: register-tiled ----------------
// out[:, g*128:(g+1)*128] = relu(h @ W[g] + b[g])
// Block: 64 rows. Thread (tx=tid&31, ty=tid>>5): cols 4tx..4tx+3, rows 8ty..8ty+7.
// LDS: Wl half [64][128] 32KB + Ht transposed [64][64] 16KB = 48KB -> 2 blocks/CU.
#define GR 64
__global__ __launch_bounds__(256) void gemm_nodes(const float* __restrict__ h,
                                                  const float* __restrict__ W,
                                                  const float* __restrict__ b,
                                                  float* __restrict__ out,
                                                  int N, int G, int g) {
    __shared__ float Wl[64 * DFEAT];   // 32 KB: W[kbase+ (0..63)][*]
    __shared__ float Ht[64 * GR];      // 16 KB: Ht[k - kbase][row]

    int tid = threadIdx.x;
    int tx = tid & 31;
    int ty = tid >> 5;
    int row0 = blockIdx.x * GR;

    float acc[8][4];
    float4 bias = ((const float4*)b)[tx];
    #pragma unroll
    for (int r = 0; r < 8; r++) {
        acc[r][0] = bias.x; acc[r][1] = bias.y; acc[r][2] = bias.z; acc[r][3] = bias.w;
    }

    for (int kbase = 0; kbase < DFEAT; kbase += 64) {
        __syncthreads();
        // stage W half: 64 rows x 128 cols, coalesced float4
        for (int i = tid; i < 64 * (DFEAT / 4); i += 256) {
            ((float4*)Wl)[i] = ((const float4*)(W + (size_t)kbase * DFEAT))[i];
        }
        // stage Ht transposed: 64 rows x 64 k-cols. ci: row=ci&63 (varies per lane
        // -> conflict-free LDS writes), c4=ci>>6 (k-chunk)
        for (int ci = tid; ci < GR * 16; ci += 256) {
            int row = ci & 63;
            int c4 = ci >> 6;
            int rr = row0 + row;
            float4 v = {0, 0, 0, 0};
            if (rr < N) v = *(const float4*)(h + (size_t)rr * DFEAT + kbase + 4 * c4);
            Ht[(4 * c4 + 0) * GR + row] = v.x;
            Ht[(4 * c4 + 1) * GR + row] = v.y;
            Ht[(4 * c4 + 2) * GR + row] = v.z;
            Ht[(4 * c4 + 3) * GR + row] = v.w;
        }
        __syncthreads();

        #pragma unroll 4
        for (int k = 0; k < 64; k++) {
            float4 wv = *(const float4*)(Wl + k * DFEAT + 4 * tx);
            float4 h0v = *(const float4*)(Ht + k * GR + 8 * ty);
            float4 h1v = *(const float4*)(Ht + k * GR + 8 * ty + 4);
            acc[0][0] += h0v.x * wv.x; acc[0][1] += h0v.x * wv.y; acc[0][2] += h0v.x * wv.z; acc[0][3] += h0v.x * wv.w;
            acc[1][0] += h0v.y * wv.x; acc[1][1] += h0v.y * wv.y; acc[1][2] += h0v.y * wv.z; acc[1][3] += h0v.y * wv.w;
            acc[2][0] += h0v.z * wv.x; acc[2][1] += h0v.z * wv.y; acc[2][2] += h0v.z * wv.z; acc[2][3] += h0v.z * wv.w;
            acc[3][0] += h0v.w * wv.x; acc[3][1] += h0v.w * wv.y; acc[3][2] += h0v.w * wv.z; acc[3][3] += h0v.w * wv.w;
            acc[4][0] += h1v.x * wv.x; acc[4][1] += h1v.x * wv.y; acc[4][2] += h1v.x * wv.z; acc[4][3] += h1v.x * wv.w;
            acc[5][0] += h1v.y * wv.x; acc[5][1] += h1v.y * wv.y; acc[5][2] += h1v.y * wv.z; acc[5][3] += h1v.y * wv.w;
            acc[6][0] += h1v.z * wv.x; acc[6][1] += h1v.z * wv.y; acc[6][2] += h1v.z * wv.z; acc[6][3] += h1v.z * wv.w;
            acc[7][0] += h1v.w * wv.x; acc[7][1] += h1v.w * wv.y; acc[7][2] += h1v.w * wv.z; acc[7][3] += h1v.w * wv.w;
        }
    }

    #pragma unroll
    for (int r = 0; r < 8; r++) {
        int row = row0 + 8 * ty + r;
        if (row < N) {
            float4 o;
            o.x = fmaxf(acc[r][0], 0.0f);
            o.y = fmaxf(acc[r][1], 0.0f);
            o.z = fmaxf(acc[r][2], 0.0f);
            o.w = fmaxf(acc[r][3], 0.0f);
            *(float4*)(out + (size_t)row * (G * DFEAT) + g * DFEAT + 4 * tx) = o;
        }
    }
}

static inline size_t align256(size_t x) { return (x + 255) & ~(size_t)255; }

extern "C" void kernel_launch(void* const* d_in, const int* in_sizes, int n_in,
                              void* d_out, int out_size, void* d_ws, size_t ws_size,
                              hipStream_t stream) {
    const float* features = (const float*)d_in[0];
    const int*   src      = (const int*)d_in[1];
    const int*   dst      = (const int*)d_in[2];
    const float* efac     = (const float*)d_in[3];
    const float* W        = (const float*)d_in[4];
    const float* b        = (const float*)d_in[5];
    float* out = (float*)d_out;

    int N = in_sizes[0] / DFEAT;
    int E = in_sizes[1];
    int G = in_sizes[3] / E;
    int nb = (N + 255) / 256;

    size_t featBytes = (size_t)N * DFEAT * sizeof(float);

    char* p = (char*)d_ws;
    float* X      = (float*)p; p += align256(featBytes);
    float* Y      = (float*)p; p += align256(featBytes);
    int*   indeg  = (int*)p;   p += align256((size_t)N * 4);
    float* norm   = (float*)p; p += align256((size_t)N * 4);
    int*   rowptr = (int*)p;   p += align256((size_t)(N + 1) * 4);
    int*   cursor = (int*)p;   p += align256((size_t)N * 4);
    int*   bsum   = (int*)p;   p += align256((size_t)nb * 4);
    int2*  epack  = (int2*)p;  p += align256((size_t)G * E * 8);

    // ---- build norm + CSR (shared across graphs) ----
    hipMemsetAsync(indeg, 0, (size_t)N * 4, stream);
    count_indeg<<<(E + 255) / 256, 256, 0, stream>>>(dst, indeg, E);
    make_norm<<<(N + 255) / 256, 256, 0, stream>>>(indeg, norm, N);
    block_sums<<<nb, 256, 0, stream>>>(indeg, bsum, N);
    scan_bsum<<<1, 256, 0, stream>>>(bsum, nb);
    scan_final<<<nb, 256, 0, stream>>>(indeg, bsum, rowptr, cursor, N);
    fill_csr<<<(E + 255) / 256, 256, 0, stream>>>(src, dst, efac, cursor, epack, E, G);

    int prepBlocks   = (N * (DFEAT / 4) + 255) / 256;
    int gatherBlocks = ((N * 32) + 255) / 256;
    int gemmBlocks   = (N + GR - 1) / GR;

    for (int g = 0; g < G; g++) {
        const int2* epg = epack + (size_t)g * E;
        // Y = features * norm
        prep_hn<<<prepBlocks, 256, 0, stream>>>(features, norm, Y, N);
        // 4 hops: Y -> X -> Y -> X -> Y
        float* bufs[2] = {X, Y};
        const float* in = Y;
        float* cur = nullptr;
        for (int hop = 0; hop < 4; hop++) {
            cur = bufs[hop & 1];
            gather_hop<<<gatherBlocks, 256, 0, stream>>>(
                in, features, norm, rowptr, epg, cur, N, hop == 3 ? 1 : 0);
            in = cur;
        }
        gemm_nodes<<<gemmBlocks, 256, 0, stream>>>(
            cur, W + (size_t)g * DFEAT * DFEAT, b + (size_t)g * DFEAT, out, N, G, g);
    }
}

// Round 4
// 437.570 us; speedup vs baseline: 25.2567x; 1.5168x over previous
//
#include <hip/hip_runtime.h>
#include <hip/hip_bf16.h>

#define DFEAT 128
#define BETA 0.1f

// ---------------- bf16 helpers ----------------
__device__ inline unsigned bf16rne(float f) {
    unsigned u = __float_as_uint(f);
    return (u + 0x7fffu + ((u >> 16) & 1u)) >> 16;
}
__device__ inline void accum8(float* a, int4 v, float w) {
    a[0] += __int_as_float(v.x << 16) * w;
    a[1] += __int_as_float(v.x & 0xffff0000) * w;
    a[2] += __int_as_float(v.y << 16) * w;
    a[3] += __int_as_float(v.y & 0xffff0000) * w;
    a[4] += __int_as_float(v.z << 16) * w;
    a[5] += __int_as_float(v.z & 0xffff0000) * w;
    a[6] += __int_as_float(v.w << 16) * w;
    a[7] += __int_as_float(v.w & 0xffff0000) * w;
}

// ---------------- in-degree count ----------------
__global__ void count_indeg(const int* __restrict__ dst, int* __restrict__ indeg, int E) {
    int e = blockIdx.x * blockDim.x + threadIdx.x;
    if (e < E) atomicAdd(&indeg[dst[e]], 1);
}

__global__ void make_norm(const int* __restrict__ indeg, float* __restrict__ norm, int N) {
    int n = blockIdx.x * blockDim.x + threadIdx.x;
    if (n < N) {
        float v = (float)(indeg[n] > 1 ? indeg[n] : 1);
        norm[n] = 1.0f / sqrtf(v);
    }
}

// ---------------- prefix scan (3-kernel) ----------------
__global__ void block_sums(const int* __restrict__ indeg, int* __restrict__ bsum, int N) {
    __shared__ int sh[256];
    int i = blockIdx.x * 256 + threadIdx.x;
    sh[threadIdx.x] = (i < N) ? indeg[i] : 0;
    __syncthreads();
    for (int s = 128; s > 0; s >>= 1) {
        if (threadIdx.x < s) sh[threadIdx.x] += sh[threadIdx.x + s];
        __syncthreads();
    }
    if (threadIdx.x == 0) bsum[blockIdx.x] = sh[0];
}

__global__ void scan_bsum(int* __restrict__ bsum, int nb) {
    __shared__ int sh[256];
    __shared__ int carry;
    if (threadIdx.x == 0) carry = 0;
    __syncthreads();
    for (int base = 0; base < nb; base += 256) {
        int i = base + threadIdx.x;
        int v = (i < nb) ? bsum[i] : 0;
        sh[threadIdx.x] = v;
        __syncthreads();
        for (int s = 1; s < 256; s <<= 1) {
            int t = (threadIdx.x >= s) ? sh[threadIdx.x - s] : 0;
            __syncthreads();
            sh[threadIdx.x] += t;
            __syncthreads();
        }
        int incl = sh[threadIdx.x];
        if (i < nb) bsum[i] = incl - v + carry;
        int total = sh[255];
        __syncthreads();
        if (threadIdx.x == 0) carry += total;
        __syncthreads();
    }
}

__global__ void scan_final(const int* __restrict__ indeg, const int* __restrict__ bsum,
                           int* __restrict__ rowptr, int* __restrict__ cursor, int N) {
    __shared__ int sh[256];
    int i = blockIdx.x * 256 + threadIdx.x;
    int v = (i < N) ? indeg[i] : 0;
    sh[threadIdx.x] = v;
    __syncthreads();
    for (int s = 1; s < 256; s <<= 1) {
        int t = (threadIdx.x >= s) ? sh[threadIdx.x - s] : 0;
        __syncthreads();
        sh[threadIdx.x] += t;
        __syncthreads();
    }
    int excl = sh[threadIdx.x] - v + bsum[blockIdx.x];
    if (i < N) { rowptr[i] = excl; cursor[i] = excl; }
    if (i == N - 1) rowptr[N] = excl + v;
}

// ------- CSR fill: counting sort by dst; w pre-scaled by (1-BETA) -------
__global__ void fill_csr(const int* __restrict__ src, const int* __restrict__ dst,
                         const float* __restrict__ efac, int* __restrict__ cursor,
                         int2* __restrict__ epack, int E, int G) {
    int e = blockIdx.x * blockDim.x + threadIdx.x;
    if (e >= E) return;
    int p = atomicAdd(&cursor[dst[e]], 1);
    int s = src[e];
    for (int g = 0; g < G; g++) {
        float w = efac[(size_t)g * E + e] * (1.0f - BETA);
        epack[(size_t)g * E + p] = make_int2(s, __float_as_int(w));
    }
}

// ------- prep: hn0b = bf16(features*norm), f0s = bf16(features*0.1) -------
__global__ void prep2(const float* __restrict__ feat, const float* __restrict__ norm,
                      unsigned* __restrict__ hnb2, unsigned* __restrict__ f0s2, int N) {
    int i = blockIdx.x * blockDim.x + threadIdx.x;   // one float4 per thread
    if (i >= N * (DFEAT / 4)) return;
    int n = i >> 5;
    float nm = norm[n];
    float4 v = ((const float4*)feat)[i];
    unsigned a0 = bf16rne(v.x * nm) | (bf16rne(v.y * nm) << 16);
    unsigned a1 = bf16rne(v.z * nm) | (bf16rne(v.w * nm) << 16);
    unsigned b0 = bf16rne(v.x * BETA) | (bf16rne(v.y * BETA) << 16);
    unsigned b1 = bf16rne(v.z * BETA) | (bf16rne(v.w * BETA) << 16);
    hnb2[2 * i] = a0; hnb2[2 * i + 1] = a1;
    f0s2[2 * i] = b0; f0s2[2 * i + 1] = b1;
}

// ---------------- gather hop (bf16 rows, 16 lanes/node) ----------------
// acc = sum_e w'[e]*hn[src[e]] ; r = acc + f0s[n]
// hops 1-3: out_b = bf16(r*norm[n]) ; hop 4: out_f = r (fp32)
__global__ __launch_bounds__(256) void gather_hop_bf16(
        const int4* __restrict__ hnb,      // bf16 rows, 16 int4 per row
        const int4* __restrict__ f0s,
        const float* __restrict__ norm,
        const int* __restrict__ rowptr, const int2* __restrict__ ep,
        int4* __restrict__ out_b, float* __restrict__ out_f,
        int N, int last) {
    int tid = blockIdx.x * blockDim.x + threadIdx.x;
    int n = tid >> 4;
    if (n >= N) return;
    int c = tid & 15;                      // 8-bf16 chunk (16 B)

    int beg = rowptr[n], end = rowptr[n + 1];
    float acc[8] = {0, 0, 0, 0, 0, 0, 0, 0};
    int i = beg;
    for (; i + 3 < end; i += 4) {
        int2 m0 = ep[i], m1 = ep[i + 1], m2 = ep[i + 2], m3 = ep[i + 3];
        int4 v0 = hnb[(size_t)m0.x * 16 + c];
        int4 v1 = hnb[(size_t)m1.x * 16 + c];
        int4 v2 = hnb[(size_t)m2.x * 16 + c];
        int4 v3 = hnb[(size_t)m3.x * 16 + c];
        accum8(acc, v0, __int_as_float(m0.y));
        accum8(acc, v1, __int_as_float(m1.y));
        accum8(acc, v2, __int_as_float(m2.y));
        accum8(acc, v3, __int_as_float(m3.y));
    }
    for (; i < end; ++i) {
        int2 m = ep[i];
        int4 v = hnb[(size_t)m.x * 16 + c];
        accum8(acc, v, __int_as_float(m.y));
    }

    int4 f = f0s[(size_t)n * 16 + c];
    float r[8];
    r[0] = acc[0] + __int_as_float(f.x << 16);
    r[1] = acc[1] + __int_as_float(f.x & 0xffff0000);
    r[2] = acc[2] + __int_as_float(f.y << 16);
    r[3] = acc[3] + __int_as_float(f.y & 0xffff0000);
    r[4] = acc[4] + __int_as_float(f.z << 16);
    r[5] = acc[5] + __int_as_float(f.z & 0xffff0000);
    r[6] = acc[6] + __int_as_float(f.w << 16);
    r[7] = acc[7] + __int_as_float(f.w & 0xffff0000);

    if (!last) {
        float nm = norm[n];
        #pragma unroll
        for (int j = 0; j < 8; j++) r[j] *= nm;
        int4 o;
        o.x = (int)(bf16rne(r[0]) | (bf16rne(r[1]) << 16));
        o.y = (int)(bf16rne(r[2]) | (bf16rne(r[3]) << 16));
        o.z = (int)(bf16rne(r[4]) | (bf16rne(r[5]) << 16));
        o.w = (int)(bf16rne(r[6]) | (bf16rne(r[7]) << 16));
        out_b[(size_t)n * 16 + c] = o;
    } else {
        float* po = out_f + (size_t)n * DFEAT + 8 * c;
        *(float4*)(po)     = make_float4(r[0], r[1], r[2], r[3]);
        *(float4*)(po + 4) = make_float4(r[4], r[5], r[6], r[7]);
    }
}

// ---------------- epilogue GEMM: register-tiled ----------------
#define GR 64
__global__ __launch_bounds__(256) void gemm_nodes(const float* __restrict__ h,
                                                  const float* __restrict__ W,
                                                  const float* __restrict__ b,
                                                  float* __restrict__ out,
                                                  int N, int G, int g) {
    __shared__ float Wl[64 * DFEAT];   // 32 KB
    __shared__ float Ht[64 * GR];      // 16 KB

    int tid = threadIdx.x;
    int tx = tid & 31;
    int ty = tid >> 5;
    int row0 = blockIdx.x * GR;

    float acc[8][4];
    float4 bias = ((const float4*)b)[tx];
    #pragma unroll
    for (int r = 0; r < 8; r++) {
        acc[r][0] = bias.x; acc[r][1] = bias.y; acc[r][2] = bias.z; acc[r][3] = bias.w;
    }

    for (int kbase = 0; kbase < DFEAT; kbase += 64) {
        __syncthreads();
        for (int i = tid; i < 64 * (DFEAT / 4); i += 256) {
            ((float4*)Wl)[i] = ((const float4*)(W + (size_t)kbase * DFEAT))[i];
        }
        for (int ci = tid; ci < GR * 16; ci += 256) {
            int row = ci & 63;
            int c4 = ci >> 6;
            int rr = row0 + row;
            float4 v = {0, 0, 0, 0};
            if (rr < N) v = *(const float4*)(h + (size_t)rr * DFEAT + kbase + 4 * c4);
            Ht[(4 * c4 + 0) * GR + row] = v.x;
            Ht[(4 * c4 + 1) * GR + row] = v.y;
            Ht[(4 * c4 + 2) * GR + row] = v.z;
            Ht[(4 * c4 + 3) * GR + row] = v.w;
        }
        __syncthreads();

        #pragma unroll 4
        for (int k = 0; k < 64; k++) {
            float4 wv = *(const float4*)(Wl + k * DFEAT + 4 * tx);
            float4 h0v = *(const float4*)(Ht + k * GR + 8 * ty);
            float4 h1v = *(const float4*)(Ht + k * GR + 8 * ty + 4);
            acc[0][0] += h0v.x * wv.x; acc[0][1] += h0v.x * wv.y; acc[0][2] += h0v.x * wv.z; acc[0][3] += h0v.x * wv.w;
            acc[1][0] += h0v.y * wv.x; acc[1][1] += h0v.y * wv.y; acc[1][2] += h0v.y * wv.z; acc[1][3] += h0v.y * wv.w;
            acc[2][0] += h0v.z * wv.x; acc[2][1] += h0v.z * wv.y; acc[2][2] += h0v.z * wv.z; acc[2][3] += h0v.z * wv.w;
            acc[3][0] += h0v.w * wv.x; acc[3][1] += h0v.w * wv.y; acc[3][2] += h0v.w * wv.z; acc[3][3] += h0v.w * wv.w;
            acc[4][0] += h1v.x * wv.x; acc[4][1] += h1v.x * wv.y; acc[4][2] += h1v.x * wv.z; acc[4][3] += h1v.x * wv.w;
            acc[5][0] += h1v.y * wv.x; acc[5][1] += h1v.y * wv.y; acc[5][2] += h1v.y * wv.z; acc[5][3] += h1v.y * wv.w;
            acc[6][0] += h1v.z * wv.x; acc[6][1] += h1v.z * wv.y; acc[6][2] += h1v.z * wv.z; acc[6][3] += h1v.z * wv.w;
            acc[7][0] += h1v.w * wv.x; acc[7][1] += h1v.w * wv.y; acc[7][2] += h1v.w * wv.z; acc[7][3] += h1v.w * wv.w;
        }
    }

    #pragma unroll
    for (int r = 0; r < 8; r++) {
        int row = row0 + 8 * ty + r;
        if (row < N) {
            float4 o;
            o.x = fmaxf(acc[r][0], 0.0f);
            o.y = fmaxf(acc[r][1], 0.0f);
            o.z = fmaxf(acc[r][2], 0.0f);
            o.w = fmaxf(acc[r][3], 0.0f);
            *(float4*)(out + (size_t)row * (G * DFEAT) + g * DFEAT + 4 * tx) = o;
        }
    }
}

static inline size_t align256(size_t x) { return (x + 255) & ~(size_t)255; }

extern "C" void kernel_launch(void* const* d_in, const int* in_sizes, int n_in,
                              void* d_out, int out_size, void* d_ws, size_t ws_size,
                              hipStream_t stream) {
    const float* features = (const float*)d_in[0];
    const int*   src      = (const int*)d_in[1];
    const int*   dst      = (const int*)d_in[2];
    const float* efac     = (const float*)d_in[3];
    const float* W        = (const float*)d_in[4];
    const float* b        = (const float*)d_in[5];
    float* out = (float*)d_out;

    int N = in_sizes[0] / DFEAT;
    int E = in_sizes[1];
    int G = in_sizes[3] / E;
    int nb = (N + 255) / 256;

    size_t featBytes  = (size_t)N * DFEAT * sizeof(float);   // 25.6 MB
    size_t bf16Bytes  = (size_t)N * DFEAT * 2;               // 12.8 MB

    char* p = (char*)d_ws;
    float*    H      = (float*)p;    p += align256(featBytes);
    int4*     Ab     = (int4*)p;     p += align256(bf16Bytes);
    int4*     hn0b   = (int4*)p;     p += align256(bf16Bytes);
    int4*     f0s    = (int4*)p;     p += align256(bf16Bytes);
    int*      indeg  = (int*)p;      p += align256((size_t)N * 4);
    float*    norm   = (float*)p;    p += align256((size_t)N * 4);
    int*      rowptr = (int*)p;      p += align256((size_t)(N + 1) * 4);
    int*      cursor = (int*)p;      p += align256((size_t)N * 4);
    int*      bsum   = (int*)p;      p += align256((size_t)nb * 4);
    int2*     epack  = (int2*)p;     p += align256((size_t)G * E * 8);

    // ---- build norm + CSR (shared across graphs) ----
    hipMemsetAsync(indeg, 0, (size_t)N * 4, stream);
    count_indeg<<<(E + 255) / 256, 256, 0, stream>>>(dst, indeg, E);
    make_norm<<<(N + 255) / 256, 256, 0, stream>>>(indeg, norm, N);
    block_sums<<<nb, 256, 0, stream>>>(indeg, bsum, N);
    scan_bsum<<<1, 256, 0, stream>>>(bsum, nb);
    scan_final<<<nb, 256, 0, stream>>>(indeg, bsum, rowptr, cursor, N);
    fill_csr<<<(E + 255) / 256, 256, 0, stream>>>(src, dst, efac, cursor, epack, E, G);

    int prepBlocks   = (N * (DFEAT / 4) + 255) / 256;
    int gatherBlocks = (N * 16 + 255) / 256;
    int gemmBlocks   = (N + GR - 1) / GR;

    for (int g = 0; g < G; g++) {
        const int2* epg = epack + (size_t)g * E;
        // hn0b = bf16(features*norm), f0s = bf16(features*0.1)
        prep2<<<prepBlocks, 256, 0, stream>>>(features, norm, (unsigned*)hn0b, (unsigned*)f0s, N);
        // hop1: hn0b -> Ab ; hop2: Ab -> hn0b ; hop3: hn0b -> Ab ; hop4: Ab -> H (fp32)
        gather_hop_bf16<<<gatherBlocks, 256, 0, stream>>>(hn0b, f0s, norm, rowptr, epg, Ab,  nullptr, N, 0);
        gather_hop_bf16<<<gatherBlocks, 256, 0, stream>>>(Ab,   f0s, norm, rowptr, epg, hn0b, nullptr, N, 0);
        gather_hop_bf16<<<gatherBlocks, 256, 0, stream>>>(hn0b, f0s, norm, rowptr, epg, Ab,  nullptr, N, 0);
        gather_hop_bf16<<<gatherBlocks, 256, 0, stream>>>(Ab,   f0s, norm, rowptr, epg, nullptr, H, N, 1);
        gemm_nodes<<<gemmBlocks, 256, 0, stream>>>(
            H, W + (size_t)g * DFEAT * DFEAT, b + (size_t)g * DFEAT, out, N, G, g);
    }
}

// Round 5
// 430.243 us; speedup vs baseline: 25.6868x; 1.0170x over previous
//
#include <hip/hip_runtime.h>
#include <hip/hip_bf16.h>

#define DFEAT 128
#define BETA 0.1f

// ---------------- bf16 helpers ----------------
__device__ inline unsigned bf16rne(float f) {
    unsigned u = __float_as_uint(f);
    return (u + 0x7fffu + ((u >> 16) & 1u)) >> 16;
}
__device__ inline void accum8(float* a, int4 v, float w) {
    a[0] += __int_as_float(v.x << 16) * w;
    a[1] += __int_as_float(v.x & 0xffff0000) * w;
    a[2] += __int_as_float(v.y << 16) * w;
    a[3] += __int_as_float(v.y & 0xffff0000) * w;
    a[4] += __int_as_float(v.z << 16) * w;
    a[5] += __int_as_float(v.z & 0xffff0000) * w;
    a[6] += __int_as_float(v.w << 16) * w;
    a[7] += __int_as_float(v.w & 0xffff0000) * w;
}

// ---------------- in-degree count ----------------
__global__ void count_indeg(const int* __restrict__ dst, int* __restrict__ indeg, int E) {
    int e = blockIdx.x * blockDim.x + threadIdx.x;
    if (e < E) atomicAdd(&indeg[dst[e]], 1);
}

__global__ void make_norm(const int* __restrict__ indeg, float* __restrict__ norm, int N) {
    int n = blockIdx.x * blockDim.x + threadIdx.x;
    if (n < N) {
        float v = (float)(indeg[n] > 1 ? indeg[n] : 1);
        norm[n] = 1.0f / sqrtf(v);
    }
}

// ---------------- prefix scan (3-kernel) ----------------
__global__ void block_sums(const int* __restrict__ indeg, int* __restrict__ bsum, int N) {
    __shared__ int sh[256];
    int i = blockIdx.x * 256 + threadIdx.x;
    sh[threadIdx.x] = (i < N) ? indeg[i] : 0;
    __syncthreads();
    for (int s = 128; s > 0; s >>= 1) {
        if (threadIdx.x < s) sh[threadIdx.x] += sh[threadIdx.x + s];
        __syncthreads();
    }
    if (threadIdx.x == 0) bsum[blockIdx.x] = sh[0];
}

__global__ void scan_bsum(int* __restrict__ bsum, int nb) {
    __shared__ int sh[256];
    __shared__ int carry;
    if (threadIdx.x == 0) carry = 0;
    __syncthreads();
    for (int base = 0; base < nb; base += 256) {
        int i = base + threadIdx.x;
        int v = (i < nb) ? bsum[i] : 0;
        sh[threadIdx.x] = v;
        __syncthreads();
        for (int s = 1; s < 256; s <<= 1) {
            int t = (threadIdx.x >= s) ? sh[threadIdx.x - s] : 0;
            __syncthreads();
            sh[threadIdx.x] += t;
            __syncthreads();
        }
        int incl = sh[threadIdx.x];
        if (i < nb) bsum[i] = incl - v + carry;
        int total = sh[255];
        __syncthreads();
        if (threadIdx.x == 0) carry += total;
        __syncthreads();
    }
}

__global__ void scan_final(const int* __restrict__ indeg, const int* __restrict__ bsum,
                           int* __restrict__ rowptr, int* __restrict__ cursor, int N) {
    __shared__ int sh[256];
    int i = blockIdx.x * 256 + threadIdx.x;
    int v = (i < N) ? indeg[i] : 0;
    sh[threadIdx.x] = v;
    __syncthreads();
    for (int s = 1; s < 256; s <<= 1) {
        int t = (threadIdx.x >= s) ? sh[threadIdx.x - s] : 0;
        __syncthreads();
        sh[threadIdx.x] += t;
        __syncthreads();
    }
    int excl = sh[threadIdx.x] - v + bsum[blockIdx.x];
    if (i < N) { rowptr[i] = excl; cursor[i] = excl; }
    if (i == N - 1) rowptr[N] = excl + v;
}

// ------- CSR fill: ONE 8B scattered write/edge for BOTH graphs -------
// epack[p] = {src, bf16(w_g0*0.9) | bf16(w_g1*0.9)<<16}
__global__ void fill_csr(const int* __restrict__ src, const int* __restrict__ dst,
                         const float* __restrict__ efac, int* __restrict__ cursor,
                         int2* __restrict__ epack, int E) {
    int e = blockIdx.x * blockDim.x + threadIdx.x;
    if (e >= E) return;
    int p = atomicAdd(&cursor[dst[e]], 1);
    float w0 = efac[e] * (1.0f - BETA);
    float w1 = efac[(size_t)E + e] * (1.0f - BETA);
    unsigned pw = bf16rne(w0) | (bf16rne(w1) << 16);
    epack[p] = make_int2(src[e], (int)pw);
}

// ------- prep: hn0b = bf16(features*norm), f0s = bf16(features*0.1) -------
__global__ void prep2(const float* __restrict__ feat, const float* __restrict__ norm,
                      unsigned* __restrict__ hnb2, unsigned* __restrict__ f0s2, int N) {
    int i = blockIdx.x * blockDim.x + threadIdx.x;   // one float4 per thread
    if (i >= N * (DFEAT / 4)) return;
    int n = i >> 5;
    float nm = norm[n];
    float4 v = ((const float4*)feat)[i];
    unsigned a0 = bf16rne(v.x * nm) | (bf16rne(v.y * nm) << 16);
    unsigned a1 = bf16rne(v.z * nm) | (bf16rne(v.w * nm) << 16);
    unsigned b0 = bf16rne(v.x * BETA) | (bf16rne(v.y * BETA) << 16);
    unsigned b1 = bf16rne(v.z * BETA) | (bf16rne(v.w * BETA) << 16);
    hnb2[2 * i] = a0; hnb2[2 * i + 1] = a1;
    f0s2[2 * i] = b0; f0s2[2 * i + 1] = b1;
}

// ---------------- gather hop (bf16 rows, 16 lanes/node, 8-deep unroll) --------
// w = bf16 half of m.y selected by wsel; acc = sum_e w*hn[src]; r = acc + f0s[n]
// hops 1-3: out_b = bf16(r*norm[n]) ; hop 4: out_f = r (fp32)
__global__ __launch_bounds__(256) void gather_hop_bf16(
        const int4* __restrict__ hnb,      // bf16 rows, 16 int4 per row
        const int4* __restrict__ f0s,
        const float* __restrict__ norm,
        const int* __restrict__ rowptr, const int2* __restrict__ ep,
        int4* __restrict__ out_b, float* __restrict__ out_f,
        int N, int last, int wsel) {
    int tid = blockIdx.x * blockDim.x + threadIdx.x;
    int n = tid >> 4;
    if (n >= N) return;
    int c = tid & 15;                      // 8-bf16 chunk (16 B)

    int beg = rowptr[n], end = rowptr[n + 1];
    int4 f = f0s[(size_t)n * 16 + c];      // issue early, consumed at the end

    float acc[8] = {0, 0, 0, 0, 0, 0, 0, 0};
    int i = beg;
    for (; i + 8 <= end; i += 8) {
        int2 m[8];
        #pragma unroll
        for (int j = 0; j < 8; j++) m[j] = ep[i + j];
        int4 v[8];
        #pragma unroll
        for (int j = 0; j < 8; j++) v[j] = hnb[(size_t)m[j].x * 16 + c];
        #pragma unroll
        for (int j = 0; j < 8; j++) {
            float w = __int_as_float(wsel ? (m[j].y & 0xffff0000) : (m[j].y << 16));
            accum8(acc, v[j], w);
        }
    }
    for (; i + 4 <= end; i += 4) {
        int2 m[4];
        #pragma unroll
        for (int j = 0; j < 4; j++) m[j] = ep[i + j];
        int4 v[4];
        #pragma unroll
        for (int j = 0; j < 4; j++) v[j] = hnb[(size_t)m[j].x * 16 + c];
        #pragma unroll
        for (int j = 0; j < 4; j++) {
            float w = __int_as_float(wsel ? (m[j].y & 0xffff0000) : (m[j].y << 16));
            accum8(acc, v[j], w);
        }
    }
    for (; i < end; ++i) {
        int2 m = ep[i];
        float w = __int_as_float(wsel ? (m.y & 0xffff0000) : (m.y << 16));
        int4 v = hnb[(size_t)m.x * 16 + c];
        accum8(acc, v, w);
    }

    float r[8];
    r[0] = acc[0] + __int_as_float(f.x << 16);
    r[1] = acc[1] + __int_as_float(f.x & 0xffff0000);
    r[2] = acc[2] + __int_as_float(f.y << 16);
    r[3] = acc[3] + __int_as_float(f.y & 0xffff0000);
    r[4] = acc[4] + __int_as_float(f.z << 16);
    r[5] = acc[5] + __int_as_float(f.z & 0xffff0000);
    r[6] = acc[6] + __int_as_float(f.w << 16);
    r[7] = acc[7] + __int_as_float(f.w & 0xffff0000);

    if (!last) {
        float nm = norm[n];
        #pragma unroll
        for (int j = 0; j < 8; j++) r[j] *= nm;
        int4 o;
        o.x = (int)(bf16rne(r[0]) | (bf16rne(r[1]) << 16));
        o.y = (int)(bf16rne(r[2]) | (bf16rne(r[3]) << 16));
        o.z = (int)(bf16rne(r[4]) | (bf16rne(r[5]) << 16));
        o.w = (int)(bf16rne(r[6]) | (bf16rne(r[7]) << 16));
        out_b[(size_t)n * 16 + c] = o;
    } else {
        float* po = out_f + (size_t)n * DFEAT + 8 * c;
        *(float4*)(po)     = make_float4(r[0], r[1], r[2], r[3]);
        *(float4*)(po + 4) = make_float4(r[4], r[5], r[6], r[7]);
    }
}

// ---------------- epilogue GEMM: register-tiled ----------------
#define GR 64
__global__ __launch_bounds__(256) void gemm_nodes(const float* __restrict__ h,
                                                  const float* __restrict__ W,
                                                  const float* __restrict__ b,
                                                  float* __restrict__ out,
                                                  int N, int G, int g) {
    __shared__ float Wl[64 * DFEAT];   // 32 KB
    __shared__ float Ht[64 * GR];      // 16 KB

    int tid = threadIdx.x;
    int tx = tid & 31;
    int ty = tid >> 5;
    int row0 = blockIdx.x * GR;

    float acc[8][4];
    float4 bias = ((const float4*)b)[tx];
    #pragma unroll
    for (int r = 0; r < 8; r++) {
        acc[r][0] = bias.x; acc[r][1] = bias.y; acc[r][2] = bias.z; acc[r][3] = bias.w;
    }

    for (int kbase = 0; kbase < DFEAT; kbase += 64) {
        __syncthreads();
        for (int i = tid; i < 64 * (DFEAT / 4); i += 256) {
            ((float4*)Wl)[i] = ((const float4*)(W + (size_t)kbase * DFEAT))[i];
        }
        for (int ci = tid; ci < GR * 16; ci += 256) {
            int row = ci & 63;
            int c4 = ci >> 6;
            int rr = row0 + row;
            float4 v = {0, 0, 0, 0};
            if (rr < N) v = *(const float4*)(h + (size_t)rr * DFEAT + kbase + 4 * c4);
            Ht[(4 * c4 + 0) * GR + row] = v.x;
            Ht[(4 * c4 + 1) * GR + row] = v.y;
            Ht[(4 * c4 + 2) * GR + row] = v.z;
            Ht[(4 * c4 + 3) * GR + row] = v.w;
        }
        __syncthreads();

        #pragma unroll 4
        for (int k = 0; k < 64; k++) {
            float4 wv = *(const float4*)(Wl + k * DFEAT + 4 * tx);
            float4 h0v = *(const float4*)(Ht + k * GR + 8 * ty);
            float4 h1v = *(const float4*)(Ht + k * GR + 8 * ty + 4);
            acc[0][0] += h0v.x * wv.x; acc[0][1] += h0v.x * wv.y; acc[0][2] += h0v.x * wv.z; acc[0][3] += h0v.x * wv.w;
            acc[1][0] += h0v.y * wv.x; acc[1][1] += h0v.y * wv.y; acc[1][2] += h0v.y * wv.z; acc[1][3] += h0v.y * wv.w;
            acc[2][0] += h0v.z * wv.x; acc[2][1] += h0v.z * wv.y; acc[2][2] += h0v.z * wv.z; acc[2][3] += h0v.z * wv.w;
            acc[3][0] += h0v.w * wv.x; acc[3][1] += h0v.w * wv.y; acc[3][2] += h0v.w * wv.z; acc[3][3] += h0v.w * wv.w;
            acc[4][0] += h1v.x * wv.x; acc[4][1] += h1v.x * wv.y; acc[4][2] += h1v.x * wv.z; acc[4][3] += h1v.x * wv.w;
            acc[5][0] += h1v.y * wv.x; acc[5][1] += h1v.y * wv.y; acc[5][2] += h1v.y * wv.z; acc[5][3] += h1v.y * wv.w;
            acc[6][0] += h1v.z * wv.x; acc[6][1] += h1v.z * wv.y; acc[6][2] += h1v.z * wv.z; acc[6][3] += h1v.z * wv.w;
            acc[7][0] += h1v.w * wv.x; acc[7][1] += h1v.w * wv.y; acc[7][2] += h1v.w * wv.z; acc[7][3] += h1v.w * wv.w;
        }
    }

    #pragma unroll
    for (int r = 0; r < 8; r++) {
        int row = row0 + 8 * ty + r;
        if (row < N) {
            float4 o;
            o.x = fmaxf(acc[r][0], 0.0f);
            o.y = fmaxf(acc[r][1], 0.0f);
            o.z = fmaxf(acc[r][2], 0.0f);
            o.w = fmaxf(acc[r][3], 0.0f);
            *(float4*)(out + (size_t)row * (G * DFEAT) + g * DFEAT + 4 * tx) = o;
        }
    }
}

static inline size_t align256(size_t x) { return (x + 255) & ~(size_t)255; }

extern "C" void kernel_launch(void* const* d_in, const int* in_sizes, int n_in,
                              void* d_out, int out_size, void* d_ws, size_t ws_size,
                              hipStream_t stream) {
    const float* features = (const float*)d_in[0];
    const int*   src      = (const int*)d_in[1];
    const int*   dst      = (const int*)d_in[2];
    const float* efac     = (const float*)d_in[3];
    const float* W        = (const float*)d_in[4];
    const float* b        = (const float*)d_in[5];
    float* out = (float*)d_out;

    int N = in_sizes[0] / DFEAT;
    int E = in_sizes[1];
    int G = in_sizes[3] / E;   // == 2
    int nb = (N + 255) / 256;

    size_t featBytes  = (size_t)N * DFEAT * sizeof(float);   // 25.6 MB
    size_t bf16Bytes  = (size_t)N * DFEAT * 2;               // 12.8 MB

    char* p = (char*)d_ws;
    float*    H      = (float*)p;    p += align256(featBytes);
    int4*     hn0b   = (int4*)p;     p += align256(bf16Bytes);
    int4*     A      = (int4*)p;     p += align256(bf16Bytes);
    int4*     B      = (int4*)p;     p += align256(bf16Bytes);
    int4*     f0s    = (int4*)p;     p += align256(bf16Bytes);
    int*      indeg  = (int*)p;      p += align256((size_t)N * 4);
    float*    norm   = (float*)p;    p += align256((size_t)N * 4);
    int*      rowptr = (int*)p;      p += align256((size_t)(N + 1) * 4);
    int*      cursor = (int*)p;      p += align256((size_t)N * 4);
    int*      bsum   = (int*)p;      p += align256((size_t)nb * 4);
    int2*     epack  = (int2*)p;     p += align256((size_t)E * 8);

    // ---- build norm + CSR (shared across graphs) ----
    hipMemsetAsync(indeg, 0, (size_t)N * 4, stream);
    count_indeg<<<(E + 255) / 256, 256, 0, stream>>>(dst, indeg, E);
    make_norm<<<(N + 255) / 256, 256, 0, stream>>>(indeg, norm, N);
    block_sums<<<nb, 256, 0, stream>>>(indeg, bsum, N);
    scan_bsum<<<1, 256, 0, stream>>>(bsum, nb);
    scan_final<<<nb, 256, 0, stream>>>(indeg, bsum, rowptr, cursor, N);
    fill_csr<<<(E + 255) / 256, 256, 0, stream>>>(src, dst, efac, cursor, epack, E);

    int prepBlocks   = (N * (DFEAT / 4) + 255) / 256;
    int gatherBlocks = (N * 16 + 255) / 256;
    int gemmBlocks   = (N + GR - 1) / GR;

    // graph-independent prep (once)
    prep2<<<prepBlocks, 256, 0, stream>>>(features, norm, (unsigned*)hn0b, (unsigned*)f0s, N);

    for (int g = 0; g < G; g++) {
        // hop1: hn0b -> A ; hop2: A -> B ; hop3: B -> A ; hop4: A -> H (fp32)
        gather_hop_bf16<<<gatherBlocks, 256, 0, stream>>>(hn0b, f0s, norm, rowptr, epack, A, nullptr, N, 0, g);
        gather_hop_bf16<<<gatherBlocks, 256, 0, stream>>>(A,    f0s, norm, rowptr, epack, B, nullptr, N, 0, g);
        gather_hop_bf16<<<gatherBlocks, 256, 0, stream>>>(B,    f0s, norm, rowptr, epack, A, nullptr, N, 0, g);
        gather_hop_bf16<<<gatherBlocks, 256, 0, stream>>>(A,    f0s, norm, rowptr, epack, nullptr, H, N, 1, g);
        gemm_nodes<<<gemmBlocks, 256, 0, stream>>>(
            H, W + (size_t)g * DFEAT * DFEAT, b + (size_t)g * DFEAT, out, N, G, g);
    }
}

// Round 6
// 413.083 us; speedup vs baseline: 26.7538x; 1.0415x over previous
//
#include <hip/hip_runtime.h>
#include <hip/hip_bf16.h>

#define DFEAT 128
#define BETA 0.1f

// ---------------- bf16 helpers ----------------
__device__ inline unsigned bf16rne(float f) {
    unsigned u = __float_as_uint(f);
    return (u + 0x7fffu + ((u >> 16) & 1u)) >> 16;
}
__device__ inline void accum8(float* a, int4 v, float w) {
    a[0] += __int_as_float(v.x << 16) * w;
    a[1] += __int_as_float(v.x & 0xffff0000) * w;
    a[2] += __int_as_float(v.y << 16) * w;
    a[3] += __int_as_float(v.y & 0xffff0000) * w;
    a[4] += __int_as_float(v.z << 16) * w;
    a[5] += __int_as_float(v.z & 0xffff0000) * w;
    a[6] += __int_as_float(v.w << 16) * w;
    a[7] += __int_as_float(v.w & 0xffff0000) * w;
}

// ---------------- in-degree count ----------------
__global__ void count_indeg(const int* __restrict__ dst, int* __restrict__ indeg, int E) {
    int e = blockIdx.x * blockDim.x + threadIdx.x;
    if (e < E) atomicAdd(&indeg[dst[e]], 1);
}

__global__ void make_norm(const int* __restrict__ indeg, float* __restrict__ norm, int N) {
    int n = blockIdx.x * blockDim.x + threadIdx.x;
    if (n < N) {
        float v = (float)(indeg[n] > 1 ? indeg[n] : 1);
        norm[n] = 1.0f / sqrtf(v);
    }
}

// ---------------- prefix scan (3-kernel) ----------------
__global__ void block_sums(const int* __restrict__ indeg, int* __restrict__ bsum, int N) {
    __shared__ int sh[256];
    int i = blockIdx.x * 256 + threadIdx.x;
    sh[threadIdx.x] = (i < N) ? indeg[i] : 0;
    __syncthreads();
    for (int s = 128; s > 0; s >>= 1) {
        if (threadIdx.x < s) sh[threadIdx.x] += sh[threadIdx.x + s];
        __syncthreads();
    }
    if (threadIdx.x == 0) bsum[blockIdx.x] = sh[0];
}

__global__ void scan_bsum(int* __restrict__ bsum, int nb) {
    __shared__ int sh[256];
    __shared__ int carry;
    if (threadIdx.x == 0) carry = 0;
    __syncthreads();
    for (int base = 0; base < nb; base += 256) {
        int i = base + threadIdx.x;
        int v = (i < nb) ? bsum[i] : 0;
        sh[threadIdx.x] = v;
        __syncthreads();
        for (int s = 1; s < 256; s <<= 1) {
            int t = (threadIdx.x >= s) ? sh[threadIdx.x - s] : 0;
            __syncthreads();
            sh[threadIdx.x] += t;
            __syncthreads();
        }
        int incl = sh[threadIdx.x];
        if (i < nb) bsum[i] = incl - v + carry;
        int total = sh[255];
        __syncthreads();
        if (threadIdx.x == 0) carry += total;
        __syncthreads();
    }
}

__global__ void scan_final(const int* __restrict__ indeg, const int* __restrict__ bsum,
                           int* __restrict__ rowptr, int* __restrict__ cursor, int N) {
    __shared__ int sh[256];
    int i = blockIdx.x * 256 + threadIdx.x;
    int v = (i < N) ? indeg[i] : 0;
    sh[threadIdx.x] = v;
    __syncthreads();
    for (int s = 1; s < 256; s <<= 1) {
        int t = (threadIdx.x >= s) ? sh[threadIdx.x - s] : 0;
        __syncthreads();
        sh[threadIdx.x] += t;
        __syncthreads();
    }
    int excl = sh[threadIdx.x] - v + bsum[blockIdx.x];
    if (i < N) { rowptr[i] = excl; cursor[i] = excl; }
    if (i == N - 1) rowptr[N] = excl + v;
}

// ------- CSR perm: 4B scattered write only -------
__global__ void fill_perm(const int* __restrict__ dst, int* __restrict__ cursor,
                          int* __restrict__ perm, int E) {
    int e = blockIdx.x * blockDim.x + threadIdx.x;
    if (e >= E) return;
    int p = atomicAdd(&cursor[dst[e]], 1);
    perm[p] = e;
}

// ------- epack materialization: sequential writes, small random reads -------
// epack[p] = {src[e], bf16(w_g0*0.9) | bf16(w_g1*0.9)<<16}
__global__ void build_epack(const int* __restrict__ perm, const int* __restrict__ src,
                            const float* __restrict__ efac, int2* __restrict__ epack, int E) {
    int p = blockIdx.x * blockDim.x + threadIdx.x;
    if (p >= E) return;
    int e = perm[p];
    float w0 = efac[e] * (1.0f - BETA);
    float w1 = efac[(size_t)E + e] * (1.0f - BETA);
    unsigned pw = bf16rne(w0) | (bf16rne(w1) << 16);
    epack[p] = make_int2(src[e], (int)pw);
}

// ------- prep: hn0b = bf16(features*norm), f0s = bf16(features*0.1) -------
__global__ void prep2(const float* __restrict__ feat, const float* __restrict__ norm,
                      unsigned* __restrict__ hnb2, unsigned* __restrict__ f0s2, int N) {
    int i = blockIdx.x * blockDim.x + threadIdx.x;   // one float4 per thread
    if (i >= N * (DFEAT / 4)) return;
    int n = i >> 5;
    float nm = norm[n];
    float4 v = ((const float4*)feat)[i];
    unsigned a0 = bf16rne(v.x * nm) | (bf16rne(v.y * nm) << 16);
    unsigned a1 = bf16rne(v.z * nm) | (bf16rne(v.w * nm) << 16);
    unsigned b0 = bf16rne(v.x * BETA) | (bf16rne(v.y * BETA) << 16);
    unsigned b1 = bf16rne(v.z * BETA) | (bf16rne(v.w * BETA) << 16);
    hnb2[2 * i] = a0; hnb2[2 * i + 1] = a1;
    f0s2[2 * i] = b0; f0s2[2 * i + 1] = b1;
}

// -------- fused dual-graph gather hop (32 lanes/node: grp=lane>>4, c=lane&15) ----
// acc = sum_e w_grp[e]*hn_grp[src]; r = acc + f0s[n]
// hops 1-3: out_grp = bf16(r*norm[n]) ; hop 4: out_grp = bf16(r)
__global__ __launch_bounds__(256) void gather_fused(
        const int4* __restrict__ hn0, const int4* __restrict__ hn1,
        const int4* __restrict__ f0s, const float* __restrict__ norm,
        const int* __restrict__ rowptr, const int2* __restrict__ ep,
        int4* __restrict__ out0, int4* __restrict__ out1,
        int N, int last) {
    int tid = blockIdx.x * blockDim.x + threadIdx.x;
    int n = tid >> 5;
    if (n >= N) return;
    int lane = tid & 31;
    int grp = lane >> 4;
    int c = lane & 15;
    const int4* hn = grp ? hn1 : hn0;

    int beg = rowptr[n], end = rowptr[n + 1];
    int4 f = f0s[(size_t)n * 16 + c];

    float acc[8] = {0, 0, 0, 0, 0, 0, 0, 0};
    int i = beg;
    for (; i + 8 <= end; i += 8) {
        int2 m[8];
        #pragma unroll
        for (int j = 0; j < 8; j++) m[j] = ep[i + j];
        int4 v[8];
        #pragma unroll
        for (int j = 0; j < 8; j++) v[j] = hn[(size_t)m[j].x * 16 + c];
        #pragma unroll
        for (int j = 0; j < 8; j++) {
            float w = __int_as_float(grp ? (m[j].y & 0xffff0000) : (m[j].y << 16));
            accum8(acc, v[j], w);
        }
    }
    for (; i + 4 <= end; i += 4) {
        int2 m[4];
        #pragma unroll
        for (int j = 0; j < 4; j++) m[j] = ep[i + j];
        int4 v[4];
        #pragma unroll
        for (int j = 0; j < 4; j++) v[j] = hn[(size_t)m[j].x * 16 + c];
        #pragma unroll
        for (int j = 0; j < 4; j++) {
            float w = __int_as_float(grp ? (m[j].y & 0xffff0000) : (m[j].y << 16));
            accum8(acc, v[j], w);
        }
    }
    for (; i < end; ++i) {
        int2 m = ep[i];
        float w = __int_as_float(grp ? (m.y & 0xffff0000) : (m.y << 16));
        int4 v = hn[(size_t)m.x * 16 + c];
        accum8(acc, v, w);
    }

    float r[8];
    r[0] = acc[0] + __int_as_float(f.x << 16);
    r[1] = acc[1] + __int_as_float(f.x & 0xffff0000);
    r[2] = acc[2] + __int_as_float(f.y << 16);
    r[3] = acc[3] + __int_as_float(f.y & 0xffff0000);
    r[4] = acc[4] + __int_as_float(f.z << 16);
    r[5] = acc[5] + __int_as_float(f.z & 0xffff0000);
    r[6] = acc[6] + __int_as_float(f.w << 16);
    r[7] = acc[7] + __int_as_float(f.w & 0xffff0000);

    if (!last) {
        float nm = norm[n];
        #pragma unroll
        for (int j = 0; j < 8; j++) r[j] *= nm;
    }
    int4 o;
    o.x = (int)(bf16rne(r[0]) | (bf16rne(r[1]) << 16));
    o.y = (int)(bf16rne(r[2]) | (bf16rne(r[3]) << 16));
    o.z = (int)(bf16rne(r[4]) | (bf16rne(r[5]) << 16));
    o.w = (int)(bf16rne(r[6]) | (bf16rne(r[7]) << 16));
    (grp ? out1 : out0)[(size_t)n * 16 + c] = o;
}

// ---------------- epilogue GEMM: register-tiled, bf16 H input ----------------
#define GR 64
__global__ __launch_bounds__(256) void gemm_nodes(const int4* __restrict__ hb,  // bf16 rows
                                                  const float* __restrict__ W,
                                                  const float* __restrict__ b,
                                                  float* __restrict__ out,
                                                  int N, int G, int g) {
    __shared__ float Wl[64 * DFEAT];   // 32 KB
    __shared__ float Ht[64 * GR];      // 16 KB

    int tid = threadIdx.x;
    int tx = tid & 31;
    int ty = tid >> 5;
    int row0 = blockIdx.x * GR;

    float acc[8][4];
    float4 bias = ((const float4*)b)[tx];
    #pragma unroll
    for (int r = 0; r < 8; r++) {
        acc[r][0] = bias.x; acc[r][1] = bias.y; acc[r][2] = bias.z; acc[r][3] = bias.w;
    }

    for (int kbase = 0; kbase < DFEAT; kbase += 64) {
        __syncthreads();
        for (int i = tid; i < 64 * (DFEAT / 4); i += 256) {
            ((float4*)Wl)[i] = ((const float4*)(W + (size_t)kbase * DFEAT))[i];
        }
        // stage Ht (fp32) from bf16 rows: ci -> row=ci&63, k8=ci>>6 (8 k-values)
        for (int ci = tid; ci < GR * 8; ci += 256) {
            int row = ci & 63;
            int k8 = ci >> 6;
            int rr = row0 + row;
            int4 v = {0, 0, 0, 0};
            if (rr < N) v = hb[(size_t)rr * 16 + (kbase >> 3) + k8];
            float* ht = Ht + (8 * k8) * GR + row;
            ht[0 * GR] = __int_as_float(v.x << 16);
            ht[1 * GR] = __int_as_float(v.x & 0xffff0000);
            ht[2 * GR] = __int_as_float(v.y << 16);
            ht[3 * GR] = __int_as_float(v.y & 0xffff0000);
            ht[4 * GR] = __int_as_float(v.z << 16);
            ht[5 * GR] = __int_as_float(v.z & 0xffff0000);
            ht[6 * GR] = __int_as_float(v.w << 16);
            ht[7 * GR] = __int_as_float(v.w & 0xffff0000);
        }
        __syncthreads();

        #pragma unroll 4
        for (int k = 0; k < 64; k++) {
            float4 wv = *(const float4*)(Wl + k * DFEAT + 4 * tx);
            float4 h0v = *(const float4*)(Ht + k * GR + 8 * ty);
            float4 h1v = *(const float4*)(Ht + k * GR + 8 * ty + 4);
            acc[0][0] += h0v.x * wv.x; acc[0][1] += h0v.x * wv.y; acc[0][2] += h0v.x * wv.z; acc[0][3] += h0v.x * wv.w;
            acc[1][0] += h0v.y * wv.x; acc[1][1] += h0v.y * wv.y; acc[1][2] += h0v.y * wv.z; acc[1][3] += h0v.y * wv.w;
            acc[2][0] += h0v.z * wv.x; acc[2][1] += h0v.z * wv.y; acc[2][2] += h0v.z * wv.z; acc[2][3] += h0v.z * wv.w;
            acc[3][0] += h0v.w * wv.x; acc[3][1] += h0v.w * wv.y; acc[3][2] += h0v.w * wv.z; acc[3][3] += h0v.w * wv.w;
            acc[4][0] += h1v.x * wv.x; acc[4][1] += h1v.x * wv.y; acc[4][2] += h1v.x * wv.z; acc[4][3] += h1v.x * wv.w;
            acc[5][0] += h1v.y * wv.x; acc[5][1] += h1v.y * wv.y; acc[5][2] += h1v.y * wv.z; acc[5][3] += h1v.y * wv.w;
            acc[6][0] += h1v.z * wv.x; acc[6][1] += h1v.z * wv.y; acc[6][2] += h1v.z * wv.z; acc[6][3] += h1v.z * wv.w;
            acc[7][0] += h1v.w * wv.x; acc[7][1] += h1v.w * wv.y; acc[7][2] += h1v.w * wv.z; acc[7][3] += h1v.w * wv.w;
        }
    }

    #pragma unroll
    for (int r = 0; r < 8; r++) {
        int row = row0 + 8 * ty + r;
        if (row < N) {
            float4 o;
            o.x = fmaxf(acc[r][0], 0.0f);
            o.y = fmaxf(acc[r][1], 0.0f);
            o.z = fmaxf(acc[r][2], 0.0f);
            o.w = fmaxf(acc[r][3], 0.0f);
            *(float4*)(out + (size_t)row * (G * DFEAT) + g * DFEAT + 4 * tx) = o;
        }
    }
}

static inline size_t align256(size_t x) { return (x + 255) & ~(size_t)255; }

extern "C" void kernel_launch(void* const* d_in, const int* in_sizes, int n_in,
                              void* d_out, int out_size, void* d_ws, size_t ws_size,
                              hipStream_t stream) {
    const float* features = (const float*)d_in[0];
    const int*   src      = (const int*)d_in[1];
    const int*   dst      = (const int*)d_in[2];
    const float* efac     = (const float*)d_in[3];
    const float* W        = (const float*)d_in[4];
    const float* b        = (const float*)d_in[5];
    float* out = (float*)d_out;

    int N = in_sizes[0] / DFEAT;
    int E = in_sizes[1];
    int G = in_sizes[3] / E;   // == 2
    int nb = (N + 255) / 256;

    size_t bf16Bytes = (size_t)N * DFEAT * 2;                // 12.8 MB

    char* p = (char*)d_ws;
    int4*  hn0b   = (int4*)p;  p += align256(bf16Bytes);
    int4*  f0s    = (int4*)p;  p += align256(bf16Bytes);
    int4*  A0     = (int4*)p;  p += align256(bf16Bytes);
    int4*  A1     = (int4*)p;  p += align256(bf16Bytes);
    int4*  B0     = (int4*)p;  p += align256(bf16Bytes);
    int4*  B1     = (int4*)p;  p += align256(bf16Bytes);
    int*   indeg  = (int*)p;   p += align256((size_t)N * 4);
    float* norm   = (float*)p; p += align256((size_t)N * 4);
    int*   rowptr = (int*)p;   p += align256((size_t)(N + 1) * 4);
    int*   cursor = (int*)p;   p += align256((size_t)N * 4);
    int*   bsum   = (int*)p;   p += align256((size_t)nb * 4);
    int2*  epack  = (int2*)p;  p += align256((size_t)E * 8);
    int*   perm   = (int*)A0;  // alias: dead before hop1 writes A0

    // ---- build norm + CSR (shared across graphs) ----
    hipMemsetAsync(indeg, 0, (size_t)N * 4, stream);
    count_indeg<<<(E + 255) / 256, 256, 0, stream>>>(dst, indeg, E);
    make_norm<<<(N + 255) / 256, 256, 0, stream>>>(indeg, norm, N);
    block_sums<<<nb, 256, 0, stream>>>(indeg, bsum, N);
    scan_bsum<<<1, 256, 0, stream>>>(bsum, nb);
    scan_final<<<nb, 256, 0, stream>>>(indeg, bsum, rowptr, cursor, N);
    fill_perm<<<(E + 255) / 256, 256, 0, stream>>>(dst, cursor, perm, E);
    build_epack<<<(E + 255) / 256, 256, 0, stream>>>(perm, src, efac, epack, E);

    int prepBlocks   = (N * (DFEAT / 4) + 255) / 256;
    int gatherBlocks = (N * 32 + 255) / 256;
    int gemmBlocks   = (N + GR - 1) / GR;

    // graph-independent prep (once)
    prep2<<<prepBlocks, 256, 0, stream>>>(features, norm, (unsigned*)hn0b, (unsigned*)f0s, N);

    // fused hops: (hn0b,hn0b) -> (A0,A1) -> (B0,B1) -> (A0,A1) -> (B0,B1)[last]
    gather_fused<<<gatherBlocks, 256, 0, stream>>>(hn0b, hn0b, f0s, norm, rowptr, epack, A0, A1, N, 0);
    gather_fused<<<gatherBlocks, 256, 0, stream>>>(A0, A1, f0s, norm, rowptr, epack, B0, B1, N, 0);
    gather_fused<<<gatherBlocks, 256, 0, stream>>>(B0, B1, f0s, norm, rowptr, epack, A0, A1, N, 0);
    gather_fused<<<gatherBlocks, 256, 0, stream>>>(A0, A1, f0s, norm, rowptr, epack, B0, B1, N, 1);

    gemm_nodes<<<gemmBlocks, 256, 0, stream>>>(B0, W,                          b,         out, N, G, 0);
    gemm_nodes<<<gemmBlocks, 256, 0, stream>>>(B1, W + (size_t)DFEAT * DFEAT, b + DFEAT, out, N, G, 1);
}